// Round 4
// baseline (228.296 us; speedup 1.0000x reference)
//
#include <hip/hip_runtime.h>
#include <math.h>

#define LSEQ  512
#define BT    128
#define INF   512
#define HH    60
#define NSTEP 1536   // 3*LSEQ
#define CH2   6      // steps per lane in scan kernel: 1536 / 256

#define MTILE 64     // rows per block (k_phi); wave owns 16 rows
#define KSTG  128    // K extent staged in LDS per stage (4 stages of 128)
#define BROW  136    // LDS B row stride in bf16 (128 + 8 pad; 2-way banks = free)

typedef __attribute__((ext_vector_type(8))) short bf16x8;
typedef __attribute__((ext_vector_type(4))) float floatx4;

// ---------- packed bf16 split via v_cvt_pk_bf16_f32 (RNE, 1 instr / 2 elts) -
__device__ __forceinline__ unsigned cvt_pk_bf16(float lo, float hi) {
  unsigned r;
  asm("v_cvt_pk_bf16_f32 %0, %1, %2" : "=v"(r) : "v"(lo), "v"(hi));
  return r;  // D[15:0]=bf16(lo), D[31:16]=bf16(hi)
}
// hw = packed high parts of (a0,a1); lw = packed residuals (a - high)
__device__ __forceinline__ void split_pair(float a0, float a1,
                                           unsigned& hw, unsigned& lw) {
  hw = cvt_pk_bf16(a0, a1);
  float h0 = __uint_as_float(hw << 16);
  float h1 = __uint_as_float(hw & 0xFFFF0000u);
  lw = cvt_pk_bf16(a0 - h0, a1 - h1);
}

// ---------- kernel 1: split-bf16 MFMA GEMM + softmax + torsion angles ------
// Latency plan: all 8 A float4-loads of a stage issue as ONE independent
// burst, double-buffered one stage ahead (issued right after the previous
// post-staging barrier) -> ~1300 cyc of cover vs ~900 cyc HBM latency, so
// the K-steps never wait on A. W is split fp32->(h,l) bf16 in-block with
// v_cvt_pk_bf16_f32 (3x fewer VALU ops than the manual integer split).
// acc += Ah*Bh + Ah*Bl + Al*Bh  (split-fp32, ~2^-17 relative).

#define ISSUE_A(BUF, KB) \
  { _Pragma("unroll") \
    for (int ks_ = 0; ks_ < 4; ++ks_) { \
      BUF[2*ks_]   = *(const float4*)(ap0 + (KB) + ks_*32); \
      BUF[2*ks_+1] = *(const float4*)(ap0 + (KB) + ks_*32 + 4); } }

#define STAGE_W(KB) \
  { _Pragma("unroll") \
    for (int i_ = 0; i_ < 8; ++i_) { \
      const int chunk_ = i_ * 256 + tid; \
      const int r_  = chunk_ >> 5; \
      const int j4_ = (chunk_ & 31) * 4; \
      float4 wv_ = make_float4(0.f, 0.f, 0.f, 0.f); \
      if (r_ < HH) wv_ = *(const float4*)(W + (size_t)r_ * INF + (KB) + j4_); \
      unsigned h01_, l01_, h23_, l23_; \
      split_pair(wv_.x, wv_.y, h01_, l01_); \
      split_pair(wv_.z, wv_.w, h23_, l23_); \
      *(uint2*)&BhL[r_ * BROW + j4_] = make_uint2(h01_, h23_); \
      *(uint2*)&BlL[r_ * BROW + j4_] = make_uint2(l01_, l23_); } }

#define DO_STEPS(BUF) \
  { _Pragma("unroll") \
    for (int ks_ = 0; ks_ < 4; ++ks_) { \
      const int kl_ = ks_ * 32; \
      float4 x_ = BUF[2*ks_], y_ = BUF[2*ks_+1]; \
      uint4 uh_, ul_; \
      split_pair(x_.x, x_.y, uh_.x, ul_.x); \
      split_pair(x_.z, x_.w, uh_.y, ul_.y); \
      split_pair(y_.x, y_.y, uh_.z, ul_.z); \
      split_pair(y_.z, y_.w, uh_.w, ul_.w); \
      bf16x8 Ah_ = __builtin_bit_cast(bf16x8, uh_); \
      bf16x8 Al_ = __builtin_bit_cast(bf16x8, ul_); \
      _Pragma("unroll") \
      for (int nt_ = 0; nt_ < 4; ++nt_) { \
        const int boff_ = (nt_ * 16 + c) * BROW + kl_ + quad * 8; \
        bf16x8 Bh_ = *(const bf16x8*)&BhL[boff_]; \
        bf16x8 Bl_ = *(const bf16x8*)&BlL[boff_]; \
        acc[nt_] = __builtin_amdgcn_mfma_f32_16x16x32_bf16(Ah_, Bh_, acc[nt_], 0, 0, 0); \
        acc[nt_] = __builtin_amdgcn_mfma_f32_16x16x32_bf16(Ah_, Bl_, acc[nt_], 0, 0, 0); \
        acc[nt_] = __builtin_amdgcn_mfma_f32_16x16x32_bf16(Al_, Bh_, acc[nt_], 0, 0, 0); } } }

__global__ __launch_bounds__(256, 3) void k_phi(
    const float* __restrict__ inp, const float* __restrict__ W,
    const float* __restrict__ bias, const float* __restrict__ alphabet,
    float* __restrict__ phi_out) {
  __shared__ unsigned short BhL[64 * BROW];   // 17408 B
  __shared__ unsigned short BlL[64 * BROW];   // 17408 B
  __shared__ float sS[HH * 3], sC[HH * 3], sBias[64];

  const int tid  = threadIdx.x;
  const int lane = tid & 63;
  const int wid  = tid >> 6;
  const int c    = lane & 15;        // frag row/col index
  const int quad = lane >> 4;        // 0..3
  const int row0 = blockIdx.x * MTILE;

  if (tid < HH * 3) { float a = alphabet[tid]; sS[tid] = __sinf(a); sC[tid] = __cosf(a); }
  if (tid >= 192 && tid < 256) { int n = tid - 192; sBias[n] = (n < HH) ? bias[n] : 0.f; }

  floatx4 acc[4];
#pragma unroll
  for (int nt = 0; nt < 4; ++nt) acc[nt] = (floatx4){0.f, 0.f, 0.f, 0.f};

  // per-lane A row base (wave owns rows wid*16 .. wid*16+15), k-offset quad*8
  const float* ap0 = inp + (size_t)(row0 + wid * 16 + c) * INF + quad * 8;

  float4 A0[8], A1[8];

  // ---- fully unrolled 4-stage schedule with 1-stage-ahead A bursts ----
  ISSUE_A(A0, 0);            // stage 0 A burst in flight
  STAGE_W(0);                // W loads overlap A latency
  __syncthreads();
  ISSUE_A(A1, KSTG);         // stage 1 A burst in flight
  DO_STEPS(A0);
  __syncthreads();
  STAGE_W(KSTG);
  __syncthreads();
  ISSUE_A(A0, 2 * KSTG);     // stage 2 A burst
  DO_STEPS(A1);
  __syncthreads();
  STAGE_W(2 * KSTG);
  __syncthreads();
  ISSUE_A(A1, 3 * KSTG);     // stage 3 A burst
  DO_STEPS(A0);
  __syncthreads();
  STAGE_W(3 * KSTG);
  __syncthreads();
  DO_STEPS(A1);

  // ---- epilogue: C/D layout row = quad*4+reg, col = lane&15 ----
#pragma unroll
  for (int reg = 0; reg < 4; ++reg) {
    float lg[4];  bool val[4];
#pragma unroll
    for (int nt = 0; nt < 4; ++nt) {
      const int n = nt * 16 + c;
      val[nt] = (n < HH);
      lg[nt] = acc[nt][reg] + sBias[n];
    }
    float m = -1e30f;
#pragma unroll
    for (int nt = 0; nt < 4; ++nt) if (val[nt]) m = fmaxf(m, lg[nt]);
#pragma unroll
    for (int d = 1; d < 16; d <<= 1) m = fmaxf(m, __shfl_xor(m, d, 64));

    float s0=0.f,c0=0.f,s1=0.f,c1=0.f,s2=0.f,c2=0.f;
#pragma unroll
    for (int nt = 0; nt < 4; ++nt) {
      const int n = nt * 16 + c;
      float e = val[nt] ? __expf(lg[nt] - m) : 0.f;
      s0 = fmaf(e, sS[n*3+0], s0);  c0 = fmaf(e, sC[n*3+0], c0);
      s1 = fmaf(e, sS[n*3+1], s1);  c1 = fmaf(e, sC[n*3+1], c1);
      s2 = fmaf(e, sS[n*3+2], s2);  c2 = fmaf(e, sC[n*3+2], c2);
    }
#pragma unroll
    for (int d = 1; d < 16; d <<= 1) {
      s0 += __shfl_xor(s0, d, 64);  c0 += __shfl_xor(c0, d, 64);
      s1 += __shfl_xor(s1, d, 64);  c1 += __shfl_xor(c1, d, 64);
      s2 += __shfl_xor(s2, d, 64);  c2 += __shfl_xor(c2, d, 64);
    }
    if (c == 0) {
      const int row = row0 + wid * 16 + quad * 4 + reg;
      const int l  = row >> 7;        // / BT
      const int bb = row & 127;       // % BT
      float* pp = phi_out + (size_t)bb * NSTEP + 3 * l;
      pp[0] = atan2f(s0, c0);
      pp[1] = atan2f(s1, c1);
      pp[2] = atan2f(s2, c2);
    }
  }
}

// ---------- rigid transform (3x3 rotation row-major + translation) ----------
struct Xf { float r[9]; float p[3]; };

__device__ __forceinline__ Xf compose(const Xf& A, const Xf& B) {
  Xf o;
#pragma unroll
  for (int i = 0; i < 3; ++i) {
#pragma unroll
    for (int j = 0; j < 3; ++j) {
      o.r[i*3+j] = fmaf(A.r[i*3+0], B.r[0+j],
                   fmaf(A.r[i*3+1], B.r[3+j],
                        A.r[i*3+2] * B.r[6+j]));
    }
    o.p[i] = fmaf(A.r[i*3+0], B.p[0],
             fmaf(A.r[i*3+1], B.p[1],
             fmaf(A.r[i*3+2], B.p[2], A.p[i])));
  }
  return o;
}

__device__ __forceinline__ Xf make_T(float phi, float st, float ct, float r) {
  float sp = __sinf(phi), cp = __cosf(phi);
  Xf T;
  T.r[0] = ct;      T.r[1] = -st;     T.r[2] = 0.f;
  T.r[3] = cp * st; T.r[4] = ct * cp; T.r[5] = -sp;
  T.r[6] = sp * st; T.r[7] = ct * sp; T.r[8] = cp;
  T.p[0] = r * ct;  T.p[1] = r * T.r[3]; T.p[2] = r * T.r[6];
  return T;
}

__device__ __forceinline__ void set_identity(Xf& X) {
  X.r[0]=1.f; X.r[1]=0.f; X.r[2]=0.f;
  X.r[3]=0.f; X.r[4]=1.f; X.r[5]=0.f;
  X.r[6]=0.f; X.r[7]=0.f; X.r[8]=1.f;
  X.p[0]=0.f; X.p[1]=0.f; X.p[2]=0.f;
}

// ---------- kernel 2: two-level parallel rigid-transform scan ---------------
__global__ __launch_bounds__(256) void k_scan(
    const float* __restrict__ phi, const float* __restrict__ bl,
    const float* __restrict__ ba, float* __restrict__ out) {
  __shared__ Xf wt[4];

  const int b = blockIdx.x;       // chain 0..127
  const int t = threadIdx.x & 63; // lane in wave
  const int w = threadIdx.x >> 6; // wave 0..3
  const int g = threadIdx.x;      // global lane 0..255

  float st[3], ct[3], rr[3];
#pragma unroll
  for (int j = 0; j < 3; ++j) {
    float a = ba[j];
    st[j] = __sinf(a); ct[j] = __cosf(a); rr[j] = bl[j];
  }

  // steps for this lane: g*6 .. g*6+5 ; (g*6+s)%3 == s%3 since 6%3==0
  float f[CH2];
  const float2* ph2 = (const float2*)(phi + (size_t)b * NSTEP + g * CH2);
#pragma unroll
  for (int q = 0; q < CH2/2; ++q) {
    float2 v = ph2[q];
    f[2*q+0] = v.x; f[2*q+1] = v.y;
  }

  Xf Q = make_T(f[0], st[0], ct[0], rr[0]);
#pragma unroll
  for (int s = 1; s < CH2; ++s)
    Q = compose(Q, make_T(f[s], st[s%3], ct[s%3], rr[s%3]));

  // wave-level inclusive scan (left-compose earlier lanes)
#pragma unroll
  for (int d = 1; d < 64; d <<= 1) {
    Xf O;
#pragma unroll
    for (int q = 0; q < 9; ++q) O.r[q] = __shfl_up(Q.r[q], d, 64);
#pragma unroll
    for (int q = 0; q < 3; ++q) O.p[q] = __shfl_up(Q.p[q], d, 64);
    if (t < d) set_identity(O);
    Q = compose(O, Q);
  }

  // cross-wave totals
  if (t == 63) wt[w] = Q;
  __syncthreads();

  // wave-local exclusive prefix
  Xf E;
#pragma unroll
  for (int q = 0; q < 9; ++q) E.r[q] = __shfl_up(Q.r[q], 1, 64);
#pragma unroll
  for (int q = 0; q < 3; ++q) E.p[q] = __shfl_up(Q.p[q], 1, 64);
  if (t == 0) set_identity(E);

  Xf S0;
  S0.r[0] = 0.f;                  S0.r[1] = 0.816496580927726f;   S0.r[2] = 0.5773502691896258f;
  S0.r[3] = -0.7071067811865475f; S0.r[4] = -0.4082482904638631f; S0.r[5] = 0.5773502691896258f;
  S0.r[6] = 0.7071067811865475f;  S0.r[7] = -0.4082482904638631f; S0.r[8] = 0.5773502691896258f;
  S0.p[0] = 0.f; S0.p[1] = 0.f; S0.p[2] = 1.f;

  // SP = S0 ∘ (wt[0] ∘ ... ∘ wt[w-1])  (wave-uniform, <=3 composes)
  Xf SP = S0;
#pragma unroll
  for (int i = 0; i < 3; ++i)
    if (i < w) SP = compose(SP, wt[i]);

  Xf cur = compose(SP, E);

  float* op = out + (size_t)(g * CH2) * (BT * 3) + b * 3;
#pragma unroll
  for (int s = 0; s < CH2; ++s) {
    cur = compose(cur, make_T(f[s], st[s%3], ct[s%3], rr[s%3]));
    op[(size_t)s * (BT*3) + 0] = cur.p[0];
    op[(size_t)s * (BT*3) + 1] = cur.p[1];
    op[(size_t)s * (BT*3) + 2] = cur.p[2];
  }
}

// ---------- launch ---------------------------------------------------------
extern "C" void kernel_launch(void* const* d_in, const int* in_sizes, int n_in,
                              void* d_out, int out_size, void* d_ws, size_t ws_size,
                              hipStream_t stream) {
  const float* inp      = (const float*)d_in[0];
  const float* W        = (const float*)d_in[1];
  const float* bias     = (const float*)d_in[2];
  const float* alphabet = (const float*)d_in[3];
  const float* bl       = (const float*)d_in[4];
  const float* ba       = (const float*)d_in[5];
  float* out = (float*)d_out;

  float* phi = (float*)d_ws;   // 786432 B

  k_phi<<<dim3((LSEQ*BT)/MTILE), dim3(256), 0, stream>>>(inp, W, bias, alphabet, phi);
  k_scan<<<dim3(BT), dim3(256), 0, stream>>>(phi, bl, ba, out);
}

// Round 5
// 212.796 us; speedup vs baseline: 1.0728x; 1.0728x over previous
//
#include <hip/hip_runtime.h>
#include <math.h>

#define LSEQ  512
#define BT    128
#define INF   512
#define HH    60
#define NSTEP 1536   // 3*LSEQ
#define CH2   6      // steps per lane in scan kernel: 1536 / 256

#define MTILE 64     // rows per block (k_phi); wave owns 16 rows
#define KSTG  128    // K extent staged per stage (4 stages of 128)
#define BROW  136    // LDS B row stride in bf16 (128 + 8 pad)

typedef __attribute__((ext_vector_type(8))) short bf16x8;
typedef __attribute__((ext_vector_type(4))) float floatx4;

// ---------- packed bf16 split via v_cvt_pk_bf16_f32 (RNE, 1 instr / 2 elts) -
__device__ __forceinline__ unsigned cvt_pk_bf16(float lo, float hi) {
  unsigned r;
  asm("v_cvt_pk_bf16_f32 %0, %1, %2" : "=v"(r) : "v"(lo), "v"(hi));
  return r;  // D[15:0]=bf16(lo), D[31:16]=bf16(hi)
}
__device__ __forceinline__ void split_pair(float a0, float a1,
                                           unsigned& hw, unsigned& lw) {
  hw = cvt_pk_bf16(a0, a1);
  float h0 = __uint_as_float(hw << 16);
  float h1 = __uint_as_float(hw & 0xFFFF0000u);
  lw = cvt_pk_bf16(a0 - h0, a1 - h1);
}

// ---------- forced-issue global load (compiler cannot sink/defer this) ------
#define GLOAD(dst, ptr, voff) \
  asm volatile("global_load_dwordx4 %0, %1, %2" \
               : "=v"(dst) : "v"(voff), "s"(ptr))

// counted wait: A[s]+W[s] done, A[s+1] (newest 8) stays in flight
#define WAIT_VM(n) \
  do { asm volatile("s_waitcnt vmcnt(" #n ")" ::: "memory"); \
       __builtin_amdgcn_sched_barrier(0); } while (0)

// raw barrier: drains LDS only, NOT vmcnt (unlike __syncthreads) ------------
#define BARRIER() \
  do { asm volatile("s_waitcnt lgkmcnt(0)" ::: "memory"); \
       __builtin_amdgcn_s_barrier(); \
       asm volatile("" ::: "memory"); } while (0)

// ---------- kernel 1: split-bf16 MFMA GEMM + softmax + torsion angles ------
// R4 failed because plain-IR prefetch loads get sunk by the scheduler
// (VGPR_Count=68 proved the burst never existed). Here every A/W global
// load is an inline-asm global_load_dwordx4 (forced issue point + forced
// registers), one counted s_waitcnt vmcnt(8) per stage, raw s_barrier with
// manual lgkmcnt. Queue per stage s: [A(s) oldest 8][W(s) 8][A(s+1) newest 8]
// -> vmcnt(8) = A(s),W(s) complete; A(s+1) rides through SPLIT_W + barrier +
// 4 K-steps (~1500 cyc of cover vs ~900 cyc HBM latency).
// acc += Ah*Bh + Ah*Bl + Al*Bh  (split-fp32, ~2^-17 relative).

#define ISSUE_A(BUF, KB) \
  { _Pragma("unroll") \
    for (int ks_ = 0; ks_ < 4; ++ks_) { \
      GLOAD(BUF[2*ks_],   aBase + (KB) + ks_*32,     voffA); \
      GLOAD(BUF[2*ks_+1], aBase + (KB) + ks_*32 + 4, voffA); } }

#define ISSUE_W(KB) \
  { _Pragma("unroll") \
    for (int i_ = 0; i_ < 7; ++i_) \
      GLOAD(Wb[i_], W + (KB) + i_*4096, voffW); \
    GLOAD(Wb[7], W + (KB) + 7*4096, voffWc); }

#define SPLIT_W() \
  { _Pragma("unroll") \
    for (int i_ = 0; i_ < 8; ++i_) { \
      const int chunk_ = i_ * 256 + tid; \
      const int r_  = chunk_ >> 5; \
      const int j4_ = (chunk_ & 31) * 4; \
      floatx4 wv_ = Wb[i_]; \
      if (i_ == 7 && tid >= 128) wv_ = (floatx4){0.f, 0.f, 0.f, 0.f}; \
      unsigned h01_, l01_, h23_, l23_; \
      split_pair(wv_[0], wv_[1], h01_, l01_); \
      split_pair(wv_[2], wv_[3], h23_, l23_); \
      *(uint2*)&BhL[r_ * BROW + j4_] = make_uint2(h01_, h23_); \
      *(uint2*)&BlL[r_ * BROW + j4_] = make_uint2(l01_, l23_); } }

#define DO_STEPS(BUF) \
  { _Pragma("unroll") \
    for (int ks_ = 0; ks_ < 4; ++ks_) { \
      const int kl_ = ks_ * 32; \
      floatx4 x_ = BUF[2*ks_], y_ = BUF[2*ks_+1]; \
      uint4 uh_, ul_; \
      split_pair(x_[0], x_[1], uh_.x, ul_.x); \
      split_pair(x_[2], x_[3], uh_.y, ul_.y); \
      split_pair(y_[0], y_[1], uh_.z, ul_.z); \
      split_pair(y_[2], y_[3], uh_.w, ul_.w); \
      bf16x8 Ah_ = __builtin_bit_cast(bf16x8, uh_); \
      bf16x8 Al_ = __builtin_bit_cast(bf16x8, ul_); \
      _Pragma("unroll") \
      for (int nt_ = 0; nt_ < 4; ++nt_) { \
        const int boff_ = (nt_ * 16 + c) * BROW + kl_ + quad * 8; \
        bf16x8 Bh_ = *(const bf16x8*)&BhL[boff_]; \
        bf16x8 Bl_ = *(const bf16x8*)&BlL[boff_]; \
        acc[nt_] = __builtin_amdgcn_mfma_f32_16x16x32_bf16(Ah_, Bh_, acc[nt_], 0, 0, 0); \
        acc[nt_] = __builtin_amdgcn_mfma_f32_16x16x32_bf16(Ah_, Bl_, acc[nt_], 0, 0, 0); \
        acc[nt_] = __builtin_amdgcn_mfma_f32_16x16x32_bf16(Al_, Bh_, acc[nt_], 0, 0, 0); } } }

__global__ __launch_bounds__(256, 3) void k_phi(
    const float* __restrict__ inp, const float* __restrict__ W,
    const float* __restrict__ bias, const float* __restrict__ alphabet,
    float* __restrict__ phi_out) {
  __shared__ unsigned short BhL[64 * BROW];   // 17408 B
  __shared__ unsigned short BlL[64 * BROW];   // 17408 B
  __shared__ float sS[HH * 3], sC[HH * 3], sBias[64];

  const int tid  = threadIdx.x;
  const int lane = tid & 63;
  const int wid  = tid >> 6;
  const int c    = lane & 15;        // frag row/col index
  const int quad = lane >> 4;        // 0..3
  const int row0 = blockIdx.x * MTILE;

  if (tid < HH * 3) { float a = alphabet[tid]; sS[tid] = __sinf(a); sC[tid] = __cosf(a); }
  if (tid >= 192 && tid < 256) { int n = tid - 192; sBias[n] = (n < HH) ? bias[n] : 0.f; }

  floatx4 acc[4];
#pragma unroll
  for (int nt = 0; nt < 4; ++nt) acc[nt] = (floatx4){0.f, 0.f, 0.f, 0.f};

  // per-lane byte voffsets; SGPR bases carry block-uniform / constant parts
  const float* aBase = inp + (size_t)row0 * INF;
  const unsigned voffA  = ((unsigned)(wid * 16 + c) * INF + quad * 8) * 4u;
  const unsigned voffW  = ((unsigned)(tid >> 5) * INF + (tid & 31) * 4) * 4u;
  const unsigned voffWc = (tid < 128) ? voffW : 0u;  // clamp OOB W rows (i=7)

  floatx4 A0[8], A1[8], Wb[8];

  // ---- stage 0 ----
  ISSUE_A(A0, 0);            // oldest 8
  ISSUE_W(0);                // +8
  ISSUE_A(A1, KSTG);         // newest 8 (rides through stage 0)
  WAIT_VM(8);                // A0 + W0 complete
  SPLIT_W();
  BARRIER();                 // publish B0 (also syncs sS/sC/sBias)
  DO_STEPS(A0);
  BARRIER();                 // B0 consumed

  // ---- stage 1 ----
  ISSUE_W(KSTG);
  ISSUE_A(A0, 2 * KSTG);
  WAIT_VM(8);                // A1 + W1 complete; A2 in flight
  SPLIT_W();
  BARRIER();
  DO_STEPS(A1);
  BARRIER();

  // ---- stage 2 ----
  ISSUE_W(2 * KSTG);
  ISSUE_A(A1, 3 * KSTG);
  WAIT_VM(8);                // A2 + W2 complete; A3 in flight
  SPLIT_W();
  BARRIER();
  DO_STEPS(A0);
  BARRIER();

  // ---- stage 3 ----
  ISSUE_W(3 * KSTG);
  WAIT_VM(0);                // A3 + W3 complete (nothing else in flight)
  SPLIT_W();
  BARRIER();
  DO_STEPS(A1);

  // ---- epilogue: C/D layout row = quad*4+reg, col = lane&15 ----
#pragma unroll
  for (int reg = 0; reg < 4; ++reg) {
    float lg[4];  bool val[4];
#pragma unroll
    for (int nt = 0; nt < 4; ++nt) {
      const int n = nt * 16 + c;
      val[nt] = (n < HH);
      lg[nt] = acc[nt][reg] + sBias[n];
    }
    float m = -1e30f;
#pragma unroll
    for (int nt = 0; nt < 4; ++nt) if (val[nt]) m = fmaxf(m, lg[nt]);
#pragma unroll
    for (int d = 1; d < 16; d <<= 1) m = fmaxf(m, __shfl_xor(m, d, 64));

    float s0=0.f,c0=0.f,s1=0.f,c1=0.f,s2=0.f,c2=0.f;
#pragma unroll
    for (int nt = 0; nt < 4; ++nt) {
      const int n = nt * 16 + c;
      float e = val[nt] ? __expf(lg[nt] - m) : 0.f;
      s0 = fmaf(e, sS[n*3+0], s0);  c0 = fmaf(e, sC[n*3+0], c0);
      s1 = fmaf(e, sS[n*3+1], s1);  c1 = fmaf(e, sC[n*3+1], c1);
      s2 = fmaf(e, sS[n*3+2], s2);  c2 = fmaf(e, sC[n*3+2], c2);
    }
#pragma unroll
    for (int d = 1; d < 16; d <<= 1) {
      s0 += __shfl_xor(s0, d, 64);  c0 += __shfl_xor(c0, d, 64);
      s1 += __shfl_xor(s1, d, 64);  c1 += __shfl_xor(c1, d, 64);
      s2 += __shfl_xor(s2, d, 64);  c2 += __shfl_xor(c2, d, 64);
    }
    if (c == 0) {
      const int row = row0 + wid * 16 + quad * 4 + reg;
      const int l  = row >> 7;        // / BT
      const int bb = row & 127;       // % BT
      float* pp = phi_out + (size_t)bb * NSTEP + 3 * l;
      pp[0] = atan2f(s0, c0);
      pp[1] = atan2f(s1, c1);
      pp[2] = atan2f(s2, c2);
    }
  }
}

// ---------- rigid transform (3x3 rotation row-major + translation) ----------
struct Xf { float r[9]; float p[3]; };

__device__ __forceinline__ Xf compose(const Xf& A, const Xf& B) {
  Xf o;
#pragma unroll
  for (int i = 0; i < 3; ++i) {
#pragma unroll
    for (int j = 0; j < 3; ++j) {
      o.r[i*3+j] = fmaf(A.r[i*3+0], B.r[0+j],
                   fmaf(A.r[i*3+1], B.r[3+j],
                        A.r[i*3+2] * B.r[6+j]));
    }
    o.p[i] = fmaf(A.r[i*3+0], B.p[0],
             fmaf(A.r[i*3+1], B.p[1],
             fmaf(A.r[i*3+2], B.p[2], A.p[i])));
  }
  return o;
}

__device__ __forceinline__ Xf make_T(float phi, float st, float ct, float r) {
  float sp = __sinf(phi), cp = __cosf(phi);
  Xf T;
  T.r[0] = ct;      T.r[1] = -st;     T.r[2] = 0.f;
  T.r[3] = cp * st; T.r[4] = ct * cp; T.r[5] = -sp;
  T.r[6] = sp * st; T.r[7] = ct * sp; T.r[8] = cp;
  T.p[0] = r * ct;  T.p[1] = r * T.r[3]; T.p[2] = r * T.r[6];
  return T;
}

__device__ __forceinline__ void set_identity(Xf& X) {
  X.r[0]=1.f; X.r[1]=0.f; X.r[2]=0.f;
  X.r[3]=0.f; X.r[4]=1.f; X.r[5]=0.f;
  X.r[6]=0.f; X.r[7]=0.f; X.r[8]=1.f;
  X.p[0]=0.f; X.p[1]=0.f; X.p[2]=0.f;
}

// ---------- kernel 2: two-level parallel rigid-transform scan ---------------
__global__ __launch_bounds__(256) void k_scan(
    const float* __restrict__ phi, const float* __restrict__ bl,
    const float* __restrict__ ba, float* __restrict__ out) {
  __shared__ Xf wt[4];

  const int b = blockIdx.x;       // chain 0..127
  const int t = threadIdx.x & 63; // lane in wave
  const int w = threadIdx.x >> 6; // wave 0..3
  const int g = threadIdx.x;      // global lane 0..255

  float st[3], ct[3], rr[3];
#pragma unroll
  for (int j = 0; j < 3; ++j) {
    float a = ba[j];
    st[j] = __sinf(a); ct[j] = __cosf(a); rr[j] = bl[j];
  }

  // steps for this lane: g*6 .. g*6+5 ; (g*6+s)%3 == s%3 since 6%3==0
  float f[CH2];
  const float2* ph2 = (const float2*)(phi + (size_t)b * NSTEP + g * CH2);
#pragma unroll
  for (int q = 0; q < CH2/2; ++q) {
    float2 v = ph2[q];
    f[2*q+0] = v.x; f[2*q+1] = v.y;
  }

  Xf Q = make_T(f[0], st[0], ct[0], rr[0]);
#pragma unroll
  for (int s = 1; s < CH2; ++s)
    Q = compose(Q, make_T(f[s], st[s%3], ct[s%3], rr[s%3]));

  // wave-level inclusive scan (left-compose earlier lanes)
#pragma unroll
  for (int d = 1; d < 64; d <<= 1) {
    Xf O;
#pragma unroll
    for (int q = 0; q < 9; ++q) O.r[q] = __shfl_up(Q.r[q], d, 64);
#pragma unroll
    for (int q = 0; q < 3; ++q) O.p[q] = __shfl_up(Q.p[q], d, 64);
    if (t < d) set_identity(O);
    Q = compose(O, Q);
  }

  // cross-wave totals
  if (t == 63) wt[w] = Q;
  __syncthreads();

  // wave-local exclusive prefix
  Xf E;
#pragma unroll
  for (int q = 0; q < 9; ++q) E.r[q] = __shfl_up(Q.r[q], 1, 64);
#pragma unroll
  for (int q = 0; q < 3; ++q) E.p[q] = __shfl_up(Q.p[q], 1, 64);
  if (t == 0) set_identity(E);

  Xf S0;
  S0.r[0] = 0.f;                  S0.r[1] = 0.816496580927726f;   S0.r[2] = 0.5773502691896258f;
  S0.r[3] = -0.7071067811865475f; S0.r[4] = -0.4082482904638631f; S0.r[5] = 0.5773502691896258f;
  S0.r[6] = 0.7071067811865475f;  S0.r[7] = -0.4082482904638631f; S0.r[8] = 0.5773502691896258f;
  S0.p[0] = 0.f; S0.p[1] = 0.f; S0.p[2] = 1.f;

  // SP = S0 ∘ (wt[0] ∘ ... ∘ wt[w-1])  (wave-uniform, <=3 composes)
  Xf SP = S0;
#pragma unroll
  for (int i = 0; i < 3; ++i)
    if (i < w) SP = compose(SP, wt[i]);

  Xf cur = compose(SP, E);

  float* op = out + (size_t)(g * CH2) * (BT * 3) + b * 3;
#pragma unroll
  for (int s = 0; s < CH2; ++s) {
    cur = compose(cur, make_T(f[s], st[s%3], ct[s%3], rr[s%3]));
    op[(size_t)s * (BT*3) + 0] = cur.p[0];
    op[(size_t)s * (BT*3) + 1] = cur.p[1];
    op[(size_t)s * (BT*3) + 2] = cur.p[2];
  }
}

// ---------- launch ---------------------------------------------------------
extern "C" void kernel_launch(void* const* d_in, const int* in_sizes, int n_in,
                              void* d_out, int out_size, void* d_ws, size_t ws_size,
                              hipStream_t stream) {
  const float* inp      = (const float*)d_in[0];
  const float* W        = (const float*)d_in[1];
  const float* bias     = (const float*)d_in[2];
  const float* alphabet = (const float*)d_in[3];
  const float* bl       = (const float*)d_in[4];
  const float* ba       = (const float*)d_in[5];
  float* out = (float*)d_out;

  float* phi = (float*)d_ws;   // 786432 B

  k_phi<<<dim3((LSEQ*BT)/MTILE), dim3(256), 0, stream>>>(inp, W, bias, alphabet, phi);
  k_scan<<<dim3(BT), dim3(256), 0, stream>>>(phi, bl, ba, out);
}